// Round 2
// baseline (599.412 us; speedup 1.0000x reference)
//
#include <hip/hip_runtime.h>

#define DEV static __device__ __forceinline__

typedef float  f32x4 __attribute__((ext_vector_type(4)));
typedef float  f32x8 __attribute__((ext_vector_type(8)));
typedef __bf16 bf16x8 __attribute__((ext_vector_type(8)));
typedef unsigned short u16x8 __attribute__((ext_vector_type(8)));

// ---------- helpers ----------
DEV unsigned short f2bf(float f) {              // RNE f32 -> bf16 bits
  unsigned u = __builtin_bit_cast(unsigned, f);
  u += 0x7FFFu + ((u >> 16) & 1u);
  return (unsigned short)(u >> 16);
}
DEV float bf2f(unsigned short h) {
  unsigned u = (unsigned)h << 16;
  return __builtin_bit_cast(float, u);
}

DEV f32x4 mfma16(u16x8 a, u16x8 b, f32x4 c) {
  return __builtin_amdgcn_mfma_f32_16x16x32_bf16(
      __builtin_bit_cast(bf16x8, a), __builtin_bit_cast(bf16x8, b), c, 0, 0, 0);
}

DEV float tanh_f(float x) {
  x = fminf(fmaxf(x, -20.f), 20.f);
  float e = __expf(2.f * x);
  return (e - 1.f) * __builtin_amdgcn_rcpf(e + 1.f);
}
DEV float sig_f(float x) { return __builtin_amdgcn_rcpf(1.f + __expf(-x)); }

DEV u16x8 byte2bf(unsigned byte) {              // 8 bits -> 8 bf16 {0,1}
  union { unsigned u[4]; u16x8 v; } r;
  #pragma unroll
  for (int i = 0; i < 4; ++i) {
    unsigned b0 = (byte >> (2 * i)) & 1u;
    unsigned b1 = (byte >> (2 * i + 1)) & 1u;
    r.u[i] = (b0 ? 0x3F80u : 0u) | (b1 ? 0x3F800000u : 0u);
  }
  return r.v;
}

// split 8 f32 -> hi/lo bf16 fragments (v = hi + lo exactly to ~2^-17)
DEV void split8(const float* p, u16x8& h, u16x8& l) {
  union { f32x4 q[2]; f32x8 o; } u;
  u.q[0] = *reinterpret_cast<const f32x4*>(p);
  u.q[1] = *reinterpret_cast<const f32x4*>(p + 4);
  #pragma unroll
  for (int i = 0; i < 8; ++i) {
    float v = u.o[i];
    unsigned short hb = f2bf(v);
    h[i] = hb;
    l[i] = f2bf(v - bf2f(hb));
  }
}

// ---------- 1) pack adjacency bits ----------
__global__ __launch_bounds__(256) void k_pack(const int* __restrict__ cfg1,
                                              const int* __restrict__ cfg2,
                                              unsigned* __restrict__ bits) {
  unsigned w = blockIdx.x * 256 + threadIdx.x;          // 0 .. 1048575
  unsigned br = w >> 19;
  unsigned rem = w & 524287u;
  const int4* p = reinterpret_cast<const int4*>(br ? cfg2 : cfg1) + rem * 8;
  unsigned m = 0;
  #pragma unroll
  for (int q = 0; q < 8; ++q) {
    int4 v = p[q];
    unsigned base = q * 4;
    m |= ((unsigned)v.x & 1u) << (base + 0);
    m |= ((unsigned)v.y & 1u) << (base + 1);
    m |= ((unsigned)v.z & 1u) << (base + 2);
    m |= ((unsigned)v.w & 1u) << (base + 3);
  }
  bits[w] = m;
}

// ---------- 2) split-precision GEMM: C = act(A[32768,K] @ W[K,NC] + b) ----------
template <int K, int NC, int ACT>
__global__ __launch_bounds__(256) void k_ff(
    const float* __restrict__ A1, const float* __restrict__ A2,
    const float* __restrict__ W1, const float* __restrict__ W2,
    const float* __restrict__ b1, const float* __restrict__ b2,
    float* __restrict__ C, int ldC, long brCstride) {
  int bid = blockIdx.x;
  int br = bid >> 8, rbk = bid & 255;
  const float* A = br ? A2 : A1;
  const float* W = br ? W2 : W1;
  const float* bias = br ? b2 : b1;

  __shared__ __attribute__((aligned(16))) unsigned short WTh[NC][K + 8];
  __shared__ __attribute__((aligned(16))) unsigned short WTl[NC][K + 8];
  for (int idx = threadIdx.x; idx < K * NC; idx += 256) {
    int k = idx / NC, c = idx % NC;
    float w = W[idx];
    unsigned short hb = f2bf(w);
    WTh[c][k] = hb;
    WTl[c][k] = f2bf(w - bf2f(hb));
  }
  __syncthreads();

  int wave = threadIdx.x >> 6, lane = threadIdx.x & 63;
  int l15 = lane & 15, g = lane >> 4;
  int row0 = rbk * 128 + wave * 32;

  f32x4 acc[2][NC / 16] = {};
  for (int kk = 0; kk < K; kk += 32) {
    u16x8 ah[2], al[2];
    #pragma unroll
    for (int rt = 0; rt < 2; ++rt)
      split8(A + (size_t)(row0 + rt * 16 + l15) * K + kk + g * 8, ah[rt], al[rt]);
    #pragma unroll
    for (int ct = 0; ct < NC / 16; ++ct) {
      u16x8 wh = *reinterpret_cast<const u16x8*>(&WTh[ct * 16 + l15][kk + g * 8]);
      u16x8 wl = *reinterpret_cast<const u16x8*>(&WTl[ct * 16 + l15][kk + g * 8]);
      #pragma unroll
      for (int rt = 0; rt < 2; ++rt) {
        acc[rt][ct] = mfma16(ah[rt], wh, acc[rt][ct]);
        acc[rt][ct] = mfma16(al[rt], wh, acc[rt][ct]);
        acc[rt][ct] = mfma16(ah[rt], wl, acc[rt][ct]);
      }
    }
  }

  float bv[NC / 16];
  #pragma unroll
  for (int ct = 0; ct < NC / 16; ++ct) bv[ct] = bias[ct * 16 + l15];
  #pragma unroll
  for (int rt = 0; rt < 2; ++rt)
    #pragma unroll
    for (int ct = 0; ct < NC / 16; ++ct)
      #pragma unroll
      for (int r = 0; r < 4; ++r) {
        float v = acc[rt][ct][r] + bv[ct];
        if (ACT) v = fmaxf(v, 0.f);
        C[(size_t)br * brCstride +
          (size_t)(row0 + rt * 16 + g * 4 + r) * ldC + ct * 16 + l15] = v;
      }
}

// ---------- 3) LSTM recurrence (fp32): one wave per (branch,batch) ----------
__global__ __launch_bounds__(64) void k_lstm(const float* __restrict__ xk,
                                             const float* __restrict__ lrk1,
                                             const float* __restrict__ lrk2,
                                             float* __restrict__ bb) {
  int br = blockIdx.x >> 6, b = blockIdx.x & 63;
  int lane = threadIdx.x;
  int u = lane & 31, hi = lane >> 5;
  int c0 = u + (hi << 5), c1 = c0 + 64;     // lo: i,g ; hi: f,o
  const float* rkp = br ? lrk2 : lrk1;
  float rk0[32], rk1[32];
  #pragma unroll
  for (int k = 0; k < 32; ++k) { rk0[k] = rkp[k * 128 + c0]; rk1[k] = rkp[k * 128 + c1]; }

  __shared__ float sh[32];
  if (lane < 32) sh[lane] = 0.f;
  float cst = 0.f;
  const float* xkb = xk + ((size_t)br * 32768 + (size_t)b * 512) * 128;
  float* bbo = bb + ((size_t)br * 32768 + (size_t)b * 512) * 64 + 32;
  float z0a = xkb[c0], z1a = xkb[c1];
  float z0b = xkb[128 + c0], z1b = xkb[128 + c1];
  __syncthreads();

  for (int t = 0; t < 512; ++t) {
    float z0n = 0.f, z1n = 0.f;
    if (t + 2 < 512) { z0n = xkb[(t + 2) * 128 + c0]; z1n = xkb[(t + 2) * 128 + c1]; }
    float a0 = z0a, a1 = z1a, a0x = 0.f, a1x = 0.f;
    #pragma unroll
    for (int k = 0; k < 32; k += 2) {
      float h0 = sh[k], h1v = sh[k + 1];
      a0 += h0 * rk0[k];      a1 += h0 * rk1[k];
      a0x += h1v * rk0[k + 1]; a1x += h1v * rk1[k + 1];
    }
    a0 += a0x; a1 += a1x;
    float s0 = sig_f(a0);                       // sig(i) | sig(f)
    float s1 = hi ? sig_f(a1) : tanh_f(a1);     // tanh(g) | sig(o)
    float aterm = s0 * s1;                      // lo: sig(i)*tanh(g)
    float fsw = __shfl_xor(s0, 32);
    float osw = __shfl_xor(s1, 32);
    __syncthreads();
    if (hi == 0) {
      cst = fsw * cst + aterm;
      float hv = osw * tanh_f(cst);
      sh[u] = hv;
      bbo[t * 64 + u] = hv;
    }
    __syncthreads();
    z0a = z0b; z1a = z1b; z0b = z0n; z1b = z1n;
  }
}

// ---------- 4) x0 = relu(bb) -> split transposed store XT_hi/XT_lo ----------
__global__ __launch_bounds__(256) void k_relu_t(const float* __restrict__ bb,
                                                unsigned short* __restrict__ XTh,
                                                unsigned short* __restrict__ XTl) {
  int bid = blockIdx.x;                       // 2*64*8
  int br = bid >> 9, rem = bid & 511, b = rem >> 3, tile = rem & 7;
  int n0 = tile * 64;
  __shared__ unsigned short xh[64][65], xl[64][65];
  const f32x4* src =
      reinterpret_cast<const f32x4*>(bb + ((size_t)(br * 64 + b) * 512 + n0) * 64);
  #pragma unroll
  for (int i = 0; i < 4; ++i) {
    int f = i * 256 + threadIdx.x;
    f32x4 v = src[f];
    int n = f >> 4, c4 = (f & 15) * 4;
    #pragma unroll
    for (int j = 0; j < 4; ++j) {
      float val = fmaxf(v[j], 0.f);
      unsigned short hb = f2bf(val);
      xh[n][c4 + j] = hb;
      xl[n][c4 + j] = f2bf(val - bf2f(hb));
    }
  }
  __syncthreads();
  int c = threadIdx.x >> 2, j0 = (threadIdx.x & 3) * 16;
  size_t base = ((size_t)(br * 64 + b) * 64 + c) * 512 + n0 + j0;
  u16x8 o0, o1, p0, p1;
  #pragma unroll
  for (int i = 0; i < 8; ++i) {
    o0[i] = xh[j0 + i][c]; o1[i] = xh[j0 + 8 + i][c];
    p0[i] = xl[j0 + i][c]; p1[i] = xl[j0 + 8 + i][c];
  }
  *reinterpret_cast<u16x8*>(XTh + base) = o0;
  *reinterpret_cast<u16x8*>(XTh + base + 8) = o1;
  *reinterpret_cast<u16x8*>(XTl + base) = p0;
  *reinterpret_cast<u16x8*>(XTl + base + 8) = p1;
}

// ---------- 5) t = adj @ (x_hi + x_lo)  (bits -> bf16 MFMA, fp32-exact) ----------
__global__ __launch_bounds__(256) void k_adj(const unsigned* __restrict__ bits,
                                             const unsigned short* __restrict__ XTh,
                                             const unsigned short* __restrict__ XTl,
                                             float* __restrict__ tout) {
  int bid = blockIdx.x;                       // 2*64*4
  int br = bid >> 8, rem = bid & 255, b = rem >> 2, rb = rem & 3;
  int wave = threadIdx.x >> 6, lane = threadIdx.x & 63;
  int l15 = lane & 15, g = lane >> 4;
  int rowbase = rb * 128 + wave * 32;
  const unsigned* bitrow0 = bits + (size_t)br * 524288 + ((size_t)b * 512 + rowbase + l15) * 16;
  const unsigned* bitrow1 = bitrow0 + 16 * 16;
  size_t xtbase = (size_t)(br * 64 + b) * 64 * 512;

  f32x4 acc[2][4] = {};
  for (int kk = 0; kk < 512; kk += 32) {
    unsigned w0 = bitrow0[kk >> 5], w1 = bitrow1[kk >> 5];
    u16x8 a0 = byte2bf((w0 >> (g * 8)) & 0xFFu);
    u16x8 a1 = byte2bf((w1 >> (g * 8)) & 0xFFu);
    u16x8 bh[4], bl[4];
    #pragma unroll
    for (int ct = 0; ct < 4; ++ct) {
      size_t off = xtbase + (size_t)(ct * 16 + l15) * 512 + kk + g * 8;
      bh[ct] = *reinterpret_cast<const u16x8*>(XTh + off);
      bl[ct] = *reinterpret_cast<const u16x8*>(XTl + off);
    }
    #pragma unroll
    for (int ct = 0; ct < 4; ++ct) {
      acc[0][ct] = mfma16(a0, bh[ct], acc[0][ct]);
      acc[0][ct] = mfma16(a0, bl[ct], acc[0][ct]);
      acc[1][ct] = mfma16(a1, bh[ct], acc[1][ct]);
      acc[1][ct] = mfma16(a1, bl[ct], acc[1][ct]);
    }
  }
  float* outb = tout + (size_t)(br * 64 + b) * 512 * 64;
  #pragma unroll
  for (int rt = 0; rt < 2; ++rt)
    #pragma unroll
    for (int ct = 0; ct < 4; ++ct)
      #pragma unroll
      for (int r = 0; r < 4; ++r)
        outb[(size_t)(rowbase + rt * 16 + g * 4 + r) * 64 + ct * 16 + l15] = acc[rt][ct][r];
}

// ---------- 6) post: two split-precision MLP layers + tanh(bb + .) ----------
template <int LAST>
__global__ __launch_bounds__(256) void k_post(const float* __restrict__ tin,
                                              const float* __restrict__ bb,
                                              const float* __restrict__ we_w,
                                              const float* __restrict__ we_b,
                                              unsigned short* __restrict__ XTh,
                                              unsigned short* __restrict__ XTl,
                                              float* __restrict__ Spart) {
  int bid = blockIdx.x;                       // 2*64*8
  int br = bid >> 9, rem = bid & 511, b = rem >> 3, tile = rem & 7;
  int n0 = tile * 64;
  __shared__ __attribute__((aligned(16))) unsigned short WT0h[64][72];
  __shared__ __attribute__((aligned(16))) unsigned short WT0l[64][72];
  __shared__ __attribute__((aligned(16))) unsigned short WT1h[64][72];
  __shared__ __attribute__((aligned(16))) unsigned short WT1l[64][72];
  __shared__ __attribute__((aligned(16))) float h1s[4][16][68];
  __shared__ unsigned short xh[64][65], xl[64][65];
  __shared__ float colsum[16][64];

  for (int idx = threadIdx.x; idx < 4096; idx += 256) {
    int k = idx >> 6, c = idx & 63;
    float w0 = we_w[k * 64 + c], w1 = we_w[4096 + k * 64 + c];
    unsigned short h0 = f2bf(w0), h1b = f2bf(w1);
    WT0h[c][k] = h0; WT0l[c][k] = f2bf(w0 - bf2f(h0));
    WT1h[c][k] = h1b; WT1l[c][k] = f2bf(w1 - bf2f(h1b));
  }
  __syncthreads();

  int wave = threadIdx.x >> 6, lane = threadIdx.x & 63;
  int l15 = lane & 15, g = lane >> 4;
  int r0 = wave * 16;
  const float* trow = tin + ((size_t)(br * 64 + b) * 512 + n0 + r0) * 64;

  f32x4 acc[4] = {};
  #pragma unroll
  for (int kk = 0; kk < 64; kk += 32) {
    u16x8 ah, al;
    split8(trow + l15 * 64 + kk + g * 8, ah, al);
    #pragma unroll
    for (int ct = 0; ct < 4; ++ct) {
      u16x8 wh = *reinterpret_cast<const u16x8*>(&WT0h[ct * 16 + l15][kk + g * 8]);
      u16x8 wl = *reinterpret_cast<const u16x8*>(&WT0l[ct * 16 + l15][kk + g * 8]);
      acc[ct] = mfma16(ah, wh, acc[ct]);
      acc[ct] = mfma16(al, wh, acc[ct]);
      acc[ct] = mfma16(ah, wl, acc[ct]);
    }
  }
  #pragma unroll
  for (int ct = 0; ct < 4; ++ct) {
    float bv = we_b[ct * 16 + l15];
    #pragma unroll
    for (int r = 0; r < 4; ++r)
      h1s[wave][g * 4 + r][ct * 16 + l15] = fmaxf(acc[ct][r] + bv, 0.f);
  }
  // wave-local LDS dependency (same wave writes then reads h1s[wave])
  f32x4 acc2[4] = {};
  #pragma unroll
  for (int kk = 0; kk < 64; kk += 32) {
    u16x8 ah, al;
    split8(&h1s[wave][l15][kk + g * 8], ah, al);
    #pragma unroll
    for (int ct = 0; ct < 4; ++ct) {
      u16x8 wh = *reinterpret_cast<const u16x8*>(&WT1h[ct * 16 + l15][kk + g * 8]);
      u16x8 wl = *reinterpret_cast<const u16x8*>(&WT1l[ct * 16 + l15][kk + g * 8]);
      acc2[ct] = mfma16(ah, wh, acc2[ct]);
      acc2[ct] = mfma16(al, wh, acc2[ct]);
      acc2[ct] = mfma16(ah, wl, acc2[ct]);
    }
  }
  const float* bbrow = bb + ((size_t)(br * 64 + b) * 512 + n0 + r0) * 64;

  if (!LAST) {
    #pragma unroll
    for (int ct = 0; ct < 4; ++ct) {
      float bv = we_b[64 + ct * 16 + l15];
      #pragma unroll
      for (int r = 0; r < 4; ++r) {
        int rr = g * 4 + r, cc = ct * 16 + l15;
        float t3 = fmaxf(acc2[ct][r] + bv, 0.f);
        float v = tanh_f(bbrow[rr * 64 + cc] + t3);
        unsigned short hb = f2bf(v);
        xh[r0 + rr][cc] = hb;
        xl[r0 + rr][cc] = f2bf(v - bf2f(hb));
      }
    }
    __syncthreads();
    int c = threadIdx.x >> 2, j0 = (threadIdx.x & 3) * 16;
    size_t base = ((size_t)(br * 64 + b) * 64 + c) * 512 + n0 + j0;
    u16x8 o0, o1, p0, p1;
    #pragma unroll
    for (int i = 0; i < 8; ++i) {
      o0[i] = xh[j0 + i][c]; o1[i] = xh[j0 + 8 + i][c];
      p0[i] = xl[j0 + i][c]; p1[i] = xl[j0 + 8 + i][c];
    }
    *reinterpret_cast<u16x8*>(XTh + base) = o0;
    *reinterpret_cast<u16x8*>(XTh + base + 8) = o1;
    *reinterpret_cast<u16x8*>(XTl + base) = p0;
    *reinterpret_cast<u16x8*>(XTl + base + 8) = p1;
  } else {
    #pragma unroll
    for (int ct = 0; ct < 4; ++ct) {
      float bv = we_b[64 + ct * 16 + l15];
      float s = 0.f;
      #pragma unroll
      for (int r = 0; r < 4; ++r) {
        int rr = g * 4 + r, cc = ct * 16 + l15;
        float t3 = fmaxf(acc2[ct][r] + bv, 0.f);
        s += tanh_f(bbrow[rr * 64 + cc] + t3);
      }
      colsum[wave * 4 + g][ct * 16 + l15] = s;
    }
    __syncthreads();
    if (threadIdx.x < 64) {
      float s = 0.f;
      #pragma unroll
      for (int q = 0; q < 16; ++q) s += colsum[q][threadIdx.x];
      Spart[((size_t)(br * 64 + b) * 8 + tile) * 64 + threadIdx.x] = s;
    }
  }
}

// ---------- 7) final: e = S@wout + bout ; cosine ----------
__global__ __launch_bounds__(64) void k_final(const float* __restrict__ Spart,
                                              const float* __restrict__ wout,
                                              const float* __restrict__ bout,
                                              float* __restrict__ out) {
  int b = blockIdx.x, c = threadIdx.x;
  __shared__ float s1s[64], s2s[64];
  float s1 = 0.f, s2 = 0.f;
  #pragma unroll
  for (int tl = 0; tl < 8; ++tl) {
    s1 += Spart[((size_t)(0 * 64 + b) * 8 + tl) * 64 + c];
    s2 += Spart[((size_t)(1 * 64 + b) * 8 + tl) * 64 + c];
  }
  s1s[c] = s1; s2s[c] = s2;
  __syncthreads();
  float e1 = bout[c], e2 = bout[c];
  for (int k = 0; k < 64; ++k) {
    float w = wout[k * 64 + c];
    e1 += s1s[k] * w;
    e2 += s2s[k] * w;
  }
  float nm = e1 * e2, dA = e1 * e1, dB = e2 * e2;
  #pragma unroll
  for (int off = 32; off; off >>= 1) {
    nm += __shfl_xor(nm, off);
    dA += __shfl_xor(dA, off);
    dB += __shfl_xor(dB, off);
  }
  if (c == 0) out[b] = nm / sqrtf(dA * dB + 1e-10f);
}

// ---------- launch ----------
extern "C" void kernel_launch(void* const* d_in, const int* in_sizes, int n_in,
                              void* d_out, int out_size, void* d_ws, size_t ws_size,
                              hipStream_t stream) {
  const int*   cfg1 = (const int*)d_in[0];
  const float* lit1 = (const float*)d_in[2];
  const float* sem1 = (const float*)d_in[3];
  const int*   cfg2 = (const int*)d_in[4];
  const float* lit2 = (const float*)d_in[6];
  const float* sem2 = (const float*)d_in[7];
  const float* d1w1 = (const float*)d_in[8];
  const float* d1b1 = (const float*)d_in[9];
  const float* d2w1 = (const float*)d_in[10];
  const float* d2b1 = (const float*)d_in[11];
  const float* lk1  = (const float*)d_in[12];
  const float* lrk1 = (const float*)d_in[13];
  const float* lb1  = (const float*)d_in[14];
  const float* d1w2 = (const float*)d_in[15];
  const float* d1b2 = (const float*)d_in[16];
  const float* d2w2 = (const float*)d_in[17];
  const float* d2b2 = (const float*)d_in[18];
  const float* lk2  = (const float*)d_in[19];
  const float* lrk2 = (const float*)d_in[20];
  const float* lb2  = (const float*)d_in[21];
  const float* we_w = (const float*)d_in[22];
  const float* we_b = (const float*)d_in[23];
  const float* wout = (const float*)d_in[24];
  const float* bout = (const float*)d_in[25];

  char* ws = (char*)d_ws;
  float* bb   = (float*)ws;                              // [2][32768][64]   16.78 MB
  float* xk   = (float*)(ws + 16777216);                 // [2][32768][128]  33.55 MB
  float* H1   = xk;                                      // alias (pre-LSTM)
  float* tbuf = xk;                                      // alias (post-LSTM) 16.78 MB
  unsigned short* XTl = (unsigned short*)(ws + 33554432); // alias in dead xk tail, 8.39 MB
  unsigned short* XTh = (unsigned short*)(ws + 50331648); // 8.39 MB
  float* Spart = (float*)(ws + 58720256);                // 256 KB
  unsigned* bits = (unsigned*)(ws + 58982400);           // 4.19 MB

  k_pack<<<4096, 256, 0, stream>>>(cfg1, cfg2, bits);

  // pre-layers (both branches per launch)
  k_ff<128, 64, 1><<<512, 256, 0, stream>>>(lit1, lit2, d1w1, d1w2, d1b1, d1b2,
                                            H1, 64, 2097152L);
  k_ff<64, 32, 1><<<512, 256, 0, stream>>>(H1, H1 + 2097152, d2w1, d2w2, d2b1, d2b2,
                                           bb, 64, 2097152L);
  k_ff<64, 128, 0><<<512, 256, 0, stream>>>(sem1, sem2, lk1, lk2, lb1, lb2,
                                            xk, 128, 4194304L);

  k_lstm<<<128, 64, 0, stream>>>(xk, lrk1, lrk2, bb);
  k_relu_t<<<1024, 256, 0, stream>>>(bb, XTh, XTl);

  for (int it = 0; it < 5; ++it) {
    k_adj<<<512, 256, 0, stream>>>(bits, XTh, XTl, tbuf);
    if (it < 4)
      k_post<0><<<1024, 256, 0, stream>>>(tbuf, bb, we_w, we_b, XTh, XTl, Spart);
    else
      k_post<1><<<1024, 256, 0, stream>>>(tbuf, bb, we_w, we_b, XTh, XTl, Spart);
  }
  k_final<<<64, 64, 0, stream>>>(Spart, wout, bout, (float*)d_out);
}